// Round 12
// baseline (30.920 us; speedup 1.0000x reference)
//
#include <hip/hip_runtime.h>
#include <hip/hip_bf16.h>

#define BT 16      // B*T
#define NN 256     // nodes
#define DD 128     // feature dim
#define HSS 136    // LDS row stride (bf16 elems): 272B = 17*16B -> aligned, bank-spread

typedef __bf16 bf16x8 __attribute__((ext_vector_type(8)));
typedef float  f32x4  __attribute__((ext_vector_type(4)));

#define LREL(z) ((z) >= 0.0f ? (z) : 0.2f * (z))

// LDS: hs[256][HSS] + bs[256][HSS] + as[16][HSS] bf16, then nbr[8][64] int
#define LDS_BYTES ((256 + 256 + 16) * HSS * 2 + 8 * 64 * 4)

// ==== Single fused kernel: block = (bt, 16-node group), 512 thr, 8 waves ====
// Phase 1a: h = x@W + bias, ALL 256 rows of this bt -> LDS   (redundant x16)
// Phase 1b: b = h@W1b + att_b1 (all rows) ; a = h@W1a (own 16 rows) -> LDS
// Phase 2 : per node: in-wave adj compaction, sparse scores, softmax,
//           aggregate, residual+LN+ReLU -> out.  All row reads from LDS.
__global__ __launch_bounds__(512, 1) void fused_kernel(
        const float* __restrict__ x, const float* __restrict__ adj,
        const float* __restrict__ weight, const float* __restrict__ bias,
        const float* __restrict__ attw1, const float* __restrict__ attb1,
        const float* __restrict__ w2, const float* __restrict__ gamma,
        const float* __restrict__ beta, float* __restrict__ out) {
    extern __shared__ char smem[];
    __bf16* hs  = (__bf16*)smem;            // [256][HSS]
    __bf16* bs  = hs + 256 * HSS;           // [256][HSS]
    __bf16* as_ = bs + 256 * HSS;           // [16][HSS]
    int*    nbr = (int*)(as_ + 16 * HSS);   // [8][64]

    int tid = threadIdx.x;
    int w = tid >> 6, l = tid & 63;
    int grp = blockIdx.x & 15, bt = blockIdx.x >> 4;
    int lrow = l & 15, lk8 = (l >> 4) * 8;
    int rsub = (l >> 4) * 4;                // MFMA D: row = rsub + r, col = lrow

    // ---------- phase 1a: h for all 256 rows; wave w owns row-tiles 2w,2w+1 ----
    bf16x8 af[2][4];
#pragma unroll
    for (int rt2 = 0; rt2 < 2; ++rt2) {
        const float* abase = x + ((size_t)bt * NN + (2 * w + rt2) * 16 + lrow) * DD + lk8;
#pragma unroll
        for (int kt = 0; kt < 4; ++kt) {
            float4 u0 = *(const float4*)(abase + 32 * kt);
            float4 u1 = *(const float4*)(abase + 32 * kt + 4);
            af[rt2][kt][0]=(__bf16)u0.x; af[rt2][kt][1]=(__bf16)u0.y;
            af[rt2][kt][2]=(__bf16)u0.z; af[rt2][kt][3]=(__bf16)u0.w;
            af[rt2][kt][4]=(__bf16)u1.x; af[rt2][kt][5]=(__bf16)u1.y;
            af[rt2][kt][6]=(__bf16)u1.z; af[rt2][kt][7]=(__bf16)u1.w;
        }
    }
#pragma unroll
    for (int ct = 0; ct < 8; ++ct) {
        int ncol = ct * 16 + lrow;
        bf16x8 wf[4];
#pragma unroll
        for (int kt = 0; kt < 4; ++kt) {
            const float* wp = weight + (size_t)(lk8 + 32 * kt) * DD + ncol;
#pragma unroll
            for (int j = 0; j < 8; ++j)
                wf[kt][j] = (__bf16)wp[(size_t)j * DD];
        }
        float bb = bias[ncol];
#pragma unroll
        for (int rt2 = 0; rt2 < 2; ++rt2) {
            f32x4 acc = {0.f, 0.f, 0.f, 0.f};
            acc = __builtin_amdgcn_mfma_f32_16x16x32_bf16(af[rt2][0], wf[0], acc, 0, 0, 0);
            acc = __builtin_amdgcn_mfma_f32_16x16x32_bf16(af[rt2][1], wf[1], acc, 0, 0, 0);
            acc = __builtin_amdgcn_mfma_f32_16x16x32_bf16(af[rt2][2], wf[2], acc, 0, 0, 0);
            acc = __builtin_amdgcn_mfma_f32_16x16x32_bf16(af[rt2][3], wf[3], acc, 0, 0, 0);
            int row0 = (2 * w + rt2) * 16 + rsub;
#pragma unroll
            for (int r = 0; r < 4; ++r)
                hs[(size_t)(row0 + r) * HSS + ncol] = (__bf16)(acc[r] + bb);
        }
    }
    __syncthreads();

    // ---------- phase 1b: b (all rows) from LDS-h; a (own 16 rows) ----------
    bf16x8 ha[2][4];
#pragma unroll
    for (int rt2 = 0; rt2 < 2; ++rt2)
#pragma unroll
        for (int kt = 0; kt < 4; ++kt)
            ha[rt2][kt] = *(const bf16x8*)&hs[(size_t)((2 * w + rt2) * 16 + lrow) * HSS
                                             + lk8 + 32 * kt];
#pragma unroll
    for (int ct = 0; ct < 8; ++ct) {
        int ncol = ct * 16 + lrow;
        bf16x8 w1f[4];
#pragma unroll
        for (int kt = 0; kt < 4; ++kt) {
            const float* wp = attw1 + (size_t)(DD + lk8 + 32 * kt) * DD + ncol;  // W1b
#pragma unroll
            for (int j = 0; j < 8; ++j)
                w1f[kt][j] = (__bf16)wp[(size_t)j * DD];
        }
        float bb = attb1[ncol];
#pragma unroll
        for (int rt2 = 0; rt2 < 2; ++rt2) {
            f32x4 acc = {0.f, 0.f, 0.f, 0.f};
            acc = __builtin_amdgcn_mfma_f32_16x16x32_bf16(ha[rt2][0], w1f[0], acc, 0, 0, 0);
            acc = __builtin_amdgcn_mfma_f32_16x16x32_bf16(ha[rt2][1], w1f[1], acc, 0, 0, 0);
            acc = __builtin_amdgcn_mfma_f32_16x16x32_bf16(ha[rt2][2], w1f[2], acc, 0, 0, 0);
            acc = __builtin_amdgcn_mfma_f32_16x16x32_bf16(ha[rt2][3], w1f[3], acc, 0, 0, 0);
            int row0 = (2 * w + rt2) * 16 + rsub;
#pragma unroll
            for (int r = 0; r < 4; ++r)
                bs[(size_t)(row0 + r) * HSS + ncol] = (__bf16)(acc[r] + bb);
        }
    }
    {   // a = h@W1a for own 16 rows; wave w computes col-tile w
        bf16x8 ho[4];
#pragma unroll
        for (int kt = 0; kt < 4; ++kt)
            ho[kt] = *(const bf16x8*)&hs[(size_t)(grp * 16 + lrow) * HSS + lk8 + 32 * kt];
        int ncol = w * 16 + lrow;
        bf16x8 w1f[4];
#pragma unroll
        for (int kt = 0; kt < 4; ++kt) {
            const float* wp = attw1 + (size_t)(lk8 + 32 * kt) * DD + ncol;       // W1a
#pragma unroll
            for (int j = 0; j < 8; ++j)
                w1f[kt][j] = (__bf16)wp[(size_t)j * DD];
        }
        f32x4 acc = {0.f, 0.f, 0.f, 0.f};
        acc = __builtin_amdgcn_mfma_f32_16x16x32_bf16(ho[0], w1f[0], acc, 0, 0, 0);
        acc = __builtin_amdgcn_mfma_f32_16x16x32_bf16(ho[1], w1f[1], acc, 0, 0, 0);
        acc = __builtin_amdgcn_mfma_f32_16x16x32_bf16(ho[2], w1f[2], acc, 0, 0, 0);
        acc = __builtin_amdgcn_mfma_f32_16x16x32_bf16(ho[3], w1f[3], acc, 0, 0, 0);
#pragma unroll
        for (int r = 0; r < 4; ++r)
            as_[(size_t)(rsub + r) * HSS + ncol] = (__bf16)acc[r];
    }
    __syncthreads();

    // ---------- phase 2: attn + LN + ReLU; wave w handles nodes 2w, 2w+1 ----
    float w20 = w2[l], w21 = w2[l + 64];
    float gm0 = gamma[l], gm1 = gamma[l + 64];
    float be0 = beta[l], be1 = beta[l + 64];

#pragma unroll
    for (int rep = 0; rep < 2; ++rep) {
        int iloc = w * 2 + rep;
        int i = grp * 16 + iloc;            // node id within bt

        // in-wave adjacency compaction
        int cnt = 0;
        const float* adjrow = adj + (size_t)i * NN;
        for (int jt = 0; jt < NN / 64; ++jt) {
            int j = jt * 64 + l;
            float v = adjrow[j];
            unsigned long long mask = __ballot(v != 0.f);
            if (v != 0.f) {
                int pos = cnt + __popcll(mask & ((1ull << l) - 1ull));
                if (pos < 64) nbr[w * 64 + pos] = j;
            }
            cnt += __popcll(mask);
        }
        cnt = min(cnt, 64);
        int jreg = nbr[w * 64 + l];

        float a0 = (float)as_[(size_t)iloc * HSS + l];
        float a1 = (float)as_[(size_t)iloc * HSS + l + 64];

        // scores: 4 neighbors/iter
        float m = -3.0e38f, myp = 0.f;
        int c = 0;
        for (; c + 3 < cnt; c += 4) {
            int j0 = __shfl(jreg, c),     j1 = __shfl(jreg, c + 1);
            int j2 = __shfl(jreg, c + 2), j3 = __shfl(jreg, c + 3);
            const __bf16* B0 = bs + (size_t)j0 * HSS;
            const __bf16* B1 = bs + (size_t)j1 * HSS;
            const __bf16* B2 = bs + (size_t)j2 * HSS;
            const __bf16* B3 = bs + (size_t)j3 * HSS;
            float p0 = LREL(a0 + (float)B0[l]) * w20 + LREL(a1 + (float)B0[l + 64]) * w21;
            float p1 = LREL(a0 + (float)B1[l]) * w20 + LREL(a1 + (float)B1[l + 64]) * w21;
            float p2 = LREL(a0 + (float)B2[l]) * w20 + LREL(a1 + (float)B2[l + 64]) * w21;
            float p3 = LREL(a0 + (float)B3[l]) * w20 + LREL(a1 + (float)B3[l + 64]) * w21;
#pragma unroll
            for (int off = 32; off; off >>= 1) {
                p0 += __shfl_xor(p0, off);
                p1 += __shfl_xor(p1, off);
                p2 += __shfl_xor(p2, off);
                p3 += __shfl_xor(p3, off);
            }
            myp = (l == c)     ? p0 : myp;
            myp = (l == c + 1) ? p1 : myp;
            myp = (l == c + 2) ? p2 : myp;
            myp = (l == c + 3) ? p3 : myp;
            m = fmaxf(m, fmaxf(fmaxf(p0, p1), fmaxf(p2, p3)));
        }
        for (; c < cnt; ++c) {
            int j0 = __shfl(jreg, c);
            const __bf16* B0 = bs + (size_t)j0 * HSS;
            float p0 = LREL(a0 + (float)B0[l]) * w20 + LREL(a1 + (float)B0[l + 64]) * w21;
#pragma unroll
            for (int off = 32; off; off >>= 1) p0 += __shfl_xor(p0, off);
            myp = (l == c) ? p0 : myp;
            m = fmaxf(m, p0);
        }

        float wgt = (l < cnt) ? __expf(myp - m) : 0.f;
        float dsum = wgt;
#pragma unroll
        for (int off = 32; off; off >>= 1) dsum += __shfl_xor(dsum, off);
        float inv = 1.f / dsum;

        // aggregate: 4 neighbors/iter from LDS h
        float acc0 = 0.f, acc1 = 0.f;
        c = 0;
        for (; c + 3 < cnt; c += 4) {
            float wc0 = __shfl(wgt, c),     wc1 = __shfl(wgt, c + 1);
            float wc2 = __shfl(wgt, c + 2), wc3 = __shfl(wgt, c + 3);
            int j0 = __shfl(jreg, c),     j1 = __shfl(jreg, c + 1);
            int j2 = __shfl(jreg, c + 2), j3 = __shfl(jreg, c + 3);
            const __bf16* H0 = hs + (size_t)j0 * HSS;
            const __bf16* H1 = hs + (size_t)j1 * HSS;
            const __bf16* H2 = hs + (size_t)j2 * HSS;
            const __bf16* H3 = hs + (size_t)j3 * HSS;
            acc0 += wc0 * (float)H0[l]      + wc1 * (float)H1[l]
                  + wc2 * (float)H2[l]      + wc3 * (float)H3[l];
            acc1 += wc0 * (float)H0[l + 64] + wc1 * (float)H1[l + 64]
                  + wc2 * (float)H2[l + 64] + wc3 * (float)H3[l + 64];
        }
        for (; c < cnt; ++c) {
            float wc = __shfl(wgt, c);
            int j = __shfl(jreg, c);
            const __bf16* H = hs + (size_t)j * HSS;
            acc0 += wc * (float)H[l];
            acc1 += wc * (float)H[l + 64];
        }

        // residual + LayerNorm + ReLU
        const float* xrow = x + ((size_t)bt * NN + i) * DD;
        float y0 = acc0 * inv + xrow[l];
        float y1 = acc1 * inv + xrow[l + 64];

        float s = y0 + y1;
#pragma unroll
        for (int off = 32; off; off >>= 1) s += __shfl_xor(s, off);
        float mu = s * (1.0f / 128.0f);
        float v0 = y0 - mu, v1 = y1 - mu;
        float vs = v0 * v0 + v1 * v1;
#pragma unroll
        for (int off = 32; off; off >>= 1) vs += __shfl_xor(vs, off);
        float rstd = rsqrtf(vs * (1.0f / 128.0f) + 1e-5f);

        float o0 = v0 * rstd * gm0 + be0;
        float o1 = v1 * rstd * gm1 + be1;

        float* orow = out + ((size_t)bt * NN + i) * DD;
        orow[l]      = fmaxf(o0, 0.0f);
        orow[l + 64] = fmaxf(o1, 0.0f);
    }
}

extern "C" void kernel_launch(void* const* d_in, const int* in_sizes, int n_in,
                              void* d_out, int out_size, void* d_ws, size_t ws_size,
                              hipStream_t stream) {
    const float* x      = (const float*)d_in[0];
    const float* adj    = (const float*)d_in[1];
    const float* weight = (const float*)d_in[2];
    const float* bias   = (const float*)d_in[3];
    const float* attw1  = (const float*)d_in[4];
    const float* attb1  = (const float*)d_in[5];
    const float* attw2  = (const float*)d_in[6];
    // d_in[7] = att_b2: uniform score shift -> cancels in softmax
    const float* gamma  = (const float*)d_in[8];
    const float* beta   = (const float*)d_in[9];
    float* out = (float*)d_out;

    fused_kernel<<<BT * 16, 512, LDS_BYTES, stream>>>(
        x, adj, weight, bias, attw1, attb1, attw2, gamma, beta, out);
}